// Round 26
// baseline (268.957 us; speedup 1.0000x reference)
//
#include <hip/hip_runtime.h>
#include <hip/hip_bf16.h>

#define B_ 4
#define N_ 2048
#define C_ 1024
#define H_ 16
#define D_ 64
#define QSCALE_ 0.1803368801f   /* 0.125 * log2(e): softmax uses exp2 */

typedef _Float16 f16;
typedef __attribute__((ext_vector_type(8))) _Float16 f16x8;
typedef __attribute__((ext_vector_type(4))) _Float16 f16x4;
typedef __attribute__((ext_vector_type(4))) float f32x4;
typedef __attribute__((ext_vector_type(16))) float f32x16;
typedef __attribute__((ext_vector_type(4))) int i32x4;
#define MFMA16(a, b, c) __builtin_amdgcn_mfma_f32_16x16x32_f16(a, b, c, 0, 0, 0)
#define MFMA32(a, b, c) __builtin_amdgcn_mfma_f32_32x32x16_f16(a, b, c, 0, 0, 0)

__device__ inline void gload_lds16(const f16* g, f16* l) {
    __builtin_amdgcn_global_load_lds(
        (const __attribute__((address_space(1))) void*)g,
        (__attribute__((address_space(3))) void*)l, 16, 0, 0);
}

__device__ inline int pkrtz(float a, float b) {
    return __builtin_bit_cast(int, __builtin_amdgcn_cvt_pkrtz(a, b));
}

// ---------------- f32 -> f16 convert (x, qkv_w, proj_w) ----------------
#define NX_ 8388608u
#define NW1_ 3145728u
#define NW2_ 1048576u

__global__ __launch_bounds__(256) void convert_kernel(
    const float* __restrict__ x, const float* __restrict__ w1, const float* __restrict__ w2,
    f16* __restrict__ xo, f16* __restrict__ w1o, f16* __restrict__ w2o)
{
    const unsigned q = blockIdx.x * 256 + threadIdx.x;
    const unsigned i = q << 2;
    const float* src;
    f16* dst;
    if (i < NX_)              { src = x  + i;               dst = xo  + i; }
    else if (i < NX_ + NW1_)  { src = w1 + (i - NX_);       dst = w1o + (i - NX_); }
    else                      { src = w2 + (i - NX_ - NW1_); dst = w2o + (i - NX_ - NW1_); }
    const float4 v = *(const float4*)src;
    f16x4 h;
    h[0] = (f16)v.x; h[1] = (f16)v.y; h[2] = (f16)v.z; h[3] = (f16)v.w;
    *(f16x4*)dst = h;
}

// ---------------- f16 MFMA GEMM: C[m][o] = sum_k A[m][k] * W[o][k] ----------------
__global__ __launch_bounds__(256) void qkv_gemm_f16(
    const f16* __restrict__ Xh,        // [8192][1024]
    const f16* __restrict__ Wh,        // [3072][1024]
    const float* __restrict__ qkv_b,
    const float* __restrict__ bias_mask,
    f16* __restrict__ Qh,              // [BH][N][D] (pre-scaled by QSCALE_)
    f16* __restrict__ Kh,              // [BH][N][D]
    f16* __restrict__ Vt)              // [BH][D][N]
{
    __shared__ f16 As[128 * 64];
    __shared__ f16 Bs[128 * 64];
    const int tid  = threadIdx.x;
    const int bm   = blockIdx.x * 128;
    const int bo   = blockIdx.y * 128;
    const int lane = tid & 63, lo = lane & 15, grp = lane >> 4;
    const int wave = tid >> 6, wr = wave >> 1, wc = wave & 1;
    const int sr = tid >> 3, cg = tid & 7;
    const int scol = (cg ^ (sr & 7)) << 3;

    f32x4 acc[4][4];
    #pragma unroll
    for (int m = 0; m < 4; ++m)
        #pragma unroll
        for (int n = 0; n < 4; ++n) acc[m][n] = f32x4{0.f, 0.f, 0.f, 0.f};

    for (int k0 = 0; k0 < 1024; k0 += 64) {
        #pragma unroll
        for (int i = 0; i < 4; ++i) {
            const int tr = i * 32 + sr;
            gload_lds16(Xh + (size_t)(bm + tr) * 1024 + k0 + scol, As + (i * 2048 + tid * 8));
            gload_lds16(Wh + (size_t)(bo + tr) * 1024 + k0 + scol, Bs + (i * 2048 + tid * 8));
        }
        __syncthreads();
        #pragma unroll
        for (int kh = 0; kh < 2; ++kh) {
            f16x8 af[4], bfr[4];
            #pragma unroll
            for (int m = 0; m < 4; ++m) {
                const int row = wr * 64 + m * 16 + lo;
                af[m] = *(const f16x8*)(As + row * 64 + ((((kh << 2) + grp) << 3) ^ ((row & 7) << 3)));
            }
            #pragma unroll
            for (int n = 0; n < 4; ++n) {
                const int row = wc * 64 + n * 16 + lo;
                bfr[n] = *(const f16x8*)(Bs + row * 64 + ((((kh << 2) + grp) << 3) ^ ((row & 7) << 3)));
            }
            #pragma unroll
            for (int m = 0; m < 4; ++m)
                #pragma unroll
                for (int n = 0; n < 4; ++n)
                    acc[m][n] = MFMA16(af[m], bfr[n], acc[m][n]);
        }
        __syncthreads();
    }
    #pragma unroll
    for (int ni = 0; ni < 4; ++ni) {
        const int o = bo + wc * 64 + ni * 16 + lo;
        const float bias = qkv_b[o] * bias_mask[o];
        const int s = o >> 10, h = (o >> 6) & 15, d = o & 63;
        #pragma unroll
        for (int mi = 0; mi < 4; ++mi) {
            #pragma unroll
            for (int r = 0; r < 4; ++r) {
                const int m = bm + wr * 64 + mi * 16 + grp * 4 + r;
                const int b = m >> 11, n = m & (N_ - 1);
                const int bh = b * H_ + h;
                const float val = acc[mi][ni][r] + bias;
                if (s == 0)      Qh[((size_t)bh * N_ + n) * D_ + d] = (f16)(val * QSCALE_);
                else if (s == 1) Kh[((size_t)bh * N_ + n) * D_ + d] = (f16)val;
                else             Vt[((size_t)bh * D_ + d) * N_ + n] = (f16)val;
            }
        }
    }
}

__global__ __launch_bounds__(256) void proj_gemm_f16(
    const f16* __restrict__ Ah,        // [8192][1024] attn out
    const f16* __restrict__ Wh,        // [1024][1024]
    const float* __restrict__ proj_b,
    float* __restrict__ Out)           // [8192][1024] f32
{
    __shared__ f16 As[128 * 64];
    __shared__ f16 Bs[128 * 64];
    const int tid  = threadIdx.x;
    const int bm   = blockIdx.x * 128;
    const int bo   = blockIdx.y * 128;
    const int lane = tid & 63, lo = lane & 15, grp = lane >> 4;
    const int wave = tid >> 6, wr = wave >> 1, wc = wave & 1;
    const int sr = tid >> 3, cg = tid & 7;
    const int scol = (cg ^ (sr & 7)) << 3;

    f32x4 acc[4][4];
    #pragma unroll
    for (int m = 0; m < 4; ++m)
        #pragma unroll
        for (int n = 0; n < 4; ++n) acc[m][n] = f32x4{0.f, 0.f, 0.f, 0.f};

    for (int k0 = 0; k0 < 1024; k0 += 64) {
        #pragma unroll
        for (int i = 0; i < 4; ++i) {
            const int tr = i * 32 + sr;
            gload_lds16(Ah + (size_t)(bm + tr) * 1024 + k0 + scol, As + (i * 2048 + tid * 8));
            gload_lds16(Wh + (size_t)(bo + tr) * 1024 + k0 + scol, Bs + (i * 2048 + tid * 8));
        }
        __syncthreads();
        #pragma unroll
        for (int kh = 0; kh < 2; ++kh) {
            f16x8 af[4], bfr[4];
            #pragma unroll
            for (int m = 0; m < 4; ++m) {
                const int row = wr * 64 + m * 16 + lo;
                af[m] = *(const f16x8*)(As + row * 64 + ((((kh << 2) + grp) << 3) ^ ((row & 7) << 3)));
            }
            #pragma unroll
            for (int n = 0; n < 4; ++n) {
                const int row = wc * 64 + n * 16 + lo;
                bfr[n] = *(const f16x8*)(Bs + row * 64 + ((((kh << 2) + grp) << 3) ^ ((row & 7) << 3)));
            }
            #pragma unroll
            for (int m = 0; m < 4; ++m)
                #pragma unroll
                for (int n = 0; n < 4; ++n)
                    acc[m][n] = MFMA16(af[m], bfr[n], acc[m][n]);
        }
        __syncthreads();
    }
    #pragma unroll
    for (int ni = 0; ni < 4; ++ni) {
        const int o = bo + wc * 64 + ni * 16 + lo;
        const float pb = proj_b[o];
        #pragma unroll
        for (int mi = 0; mi < 4; ++mi) {
            #pragma unroll
            for (int r = 0; r < 4; ++r) {
                const int m = bm + wr * 64 + mi * 16 + grp * 4 + r;
                Out[(size_t)m * C_ + o] = acc[mi][ni][r] + pb;
            }
        }
    }
}

// ---------------- 8-wave KVBLK=128 flash attention, V direct from L2 (attn_fa17) ----------------
// fa16 with V staging removed: V^T frags read per-lane from global (L2-resident
// via the XCD swizzle; compiler inserts waits). LDS halves to 32 KB (K dbuf only)
// -> 3-4 blocks/CU residency. K staging: 2 loads/thread -> vmcnt(2).
__global__ __launch_bounds__(512) void attn_fa17_kernel(
    const f16* __restrict__ Qb,  // [BH][N][D] (scaled by QSCALE_)
    const f16* __restrict__ Kb,  // [BH][N][D]
    const f16* __restrict__ Vt,  // [BH][D][N]
    f16* __restrict__ AO)        // [B][N][C] f16
{
    __shared__ f16 Kt[2][128 * 64];
    const int tid  = threadIdx.x;
    const int lane = tid & 63;
    const int lo   = lane & 31;
    const int hi   = lane >> 5;
    const int wave = tid >> 6;               // 0..7

    const int id   = blockIdx.x;             // 0..511
    const int xcd  = id & 7;
    const int j    = id >> 3;                // 0..63
    const int bh   = (xcd << 3) | (j >> 3);  // 8 heads per XCD (L2-resident K/V)
    const int q0   = (j & 7) * 256 + wave * 32;
    const size_t base = (size_t)bh * (N_ * D_);

    const f16* Kp = Kb + base;
    const f16* Vp = Vt + base;
    const f16* vrow0 = Vp + (size_t)lo * N_;         // row d' = lo
    const f16* vrow1 = Vp + (size_t)(32 + lo) * N_;  // row d' = 32+lo

    f16x8 qf[4];
    #pragma unroll
    for (int dc = 0; dc < 4; ++dc)
        qf[dc] = *(const f16x8*)(Qb + base + (size_t)(q0 + lo) * D_ + dc * 16 + hi * 8);

    // stage a 128-kv K tile: 1024 slots, 512 threads -> 2 slots/thread.
#define STAGE_K(BK, KV0)                                                           \
    { _Pragma("unroll") for (int i_ = 0; i_ < 2; ++i_) {                           \
        const int si_ = i_ * 512 + tid;                                            \
        const int krow_ = si_ >> 3, kgrp_ = si_ & 7;                               \
        gload_lds16(Kp + (size_t)((KV0) + krow_) * D_ + ((kgrp_ ^ (krow_ & 7)) << 3), \
                    (BK) + si_ * 8);                                               \
      } }

// in-register P redistribution (validated in fa14/fa15/fa16)
#define P_TO_FRAGS(P, PB1, PB2)                                                    \
    { int d0_ = pkrtz(P[0],  P[1]),  d1_ = pkrtz(P[2],  P[3]);                     \
      int d2_ = pkrtz(P[4],  P[5]),  d3_ = pkrtz(P[6],  P[7]);                     \
      int d4_ = pkrtz(P[8],  P[9]),  d5_ = pkrtz(P[10], P[11]);                    \
      int d6_ = pkrtz(P[12], P[13]), d7_ = pkrtz(P[14], P[15]);                    \
      const int x0_ = __shfl_xor(d0_, 32, 64), x1_ = __shfl_xor(d1_, 32, 64);      \
      const int x2_ = __shfl_xor(d2_, 32, 64), x3_ = __shfl_xor(d3_, 32, 64);      \
      const int x4_ = __shfl_xor(d4_, 32, 64), x5_ = __shfl_xor(d5_, 32, 64);      \
      const int x6_ = __shfl_xor(d6_, 32, 64), x7_ = __shfl_xor(d7_, 32, 64);      \
      i32x4 w1_, w2_;                                                              \
      w1_[0] = hi ? x2_ : d0_;  w1_[1] = hi ? x3_ : d1_;                           \
      w1_[2] = hi ? d2_ : x0_;  w1_[3] = hi ? d3_ : x1_;                           \
      w2_[0] = hi ? x6_ : d4_;  w2_[1] = hi ? x7_ : d5_;                           \
      w2_[2] = hi ? d6_ : x4_;  w2_[3] = hi ? d7_ : x5_;                           \
      PB1 = __builtin_bit_cast(f16x8, w1_);                                        \
      PB2 = __builtin_bit_cast(f16x8, w2_); }

    const f32x16 zero16 = {};
    f32x16 o0 = zero16, o1 = zero16;   // O^T: reg r = O[d=(dh*32)+(r&3)+8(r>>2)+4hi][q=lo]
    float lsum = 0.f;                  // own-half partial; combined in epilogue
    const int kx = (lo & 7) << 3;      // K swizzle key

    STAGE_K(Kt[0], 0);
    int cur = 0;

    for (int t = 0; t < 16; ++t) {
        const int kvb = t * 128;
        const int nxt = (t < 15) ? (t + 1) * 128 : 0;
        STAGE_K(Kt[cur ^ 1], nxt);
        asm volatile("s_waitcnt vmcnt(2)" ::: "memory");   // K tile t landed; next 2 in flight
        __builtin_amdgcn_s_barrier();
        __builtin_amdgcn_sched_barrier(0);

        const f16* kb = Kt[cur];

        #pragma unroll
        for (int c = 0; c < 4; ++c) {
            f16x8 kf[4];
            #pragma unroll
            for (int dc = 0; dc < 4; ++dc)
                kf[dc] = *(const f16x8*)(kb + (c * 32 + lo) * 64 + ((((dc * 2 + hi) << 3)) ^ kx));
            __builtin_amdgcn_s_setprio(1);
            f32x16 s = MFMA32(kf[0], qf[0], zero16);
            s = MFMA32(kf[1], qf[1], s);
            s = MFMA32(kf[2], qf[2], s);
            s = MFMA32(kf[3], qf[3], s);
            __builtin_amdgcn_s_setprio(0);

            // V^T frags direct from global (L2-hit): rows lo / 32+lo, cols kvb+c*32+{0,16}+hi*8
            const int vc = kvb + c * 32 + hi * 8;
            const f16x8 vf00 = *(const f16x8*)(vrow0 + vc);
            const f16x8 vf01 = *(const f16x8*)(vrow0 + vc + 16);
            const f16x8 vf10 = *(const f16x8*)(vrow1 + vc);
            const f16x8 vf11 = *(const f16x8*)(vrow1 + vc + 16);

            float p[16];
            #pragma unroll
            for (int r = 0; r < 16; ++r) p[r] = __builtin_amdgcn_exp2f(s[r]);
            lsum += (((p[0]+p[1])+(p[2]+p[3])) + ((p[4]+p[5])+(p[6]+p[7])))
                  + (((p[8]+p[9])+(p[10]+p[11])) + ((p[12]+p[13])+(p[14]+p[15])));
            f16x8 pb1, pb2;
            P_TO_FRAGS(p, pb1, pb2);

            __builtin_amdgcn_s_setprio(1);
            o0 = MFMA32(vf00, pb1, o0);
            o0 = MFMA32(vf01, pb2, o0);
            o1 = MFMA32(vf10, pb1, o1);
            o1 = MFMA32(vf11, pb2, o1);
            __builtin_amdgcn_s_setprio(0);
        }

        __builtin_amdgcn_sched_barrier(0);
        __builtin_amdgcn_s_barrier();      // raw: protect K buffer overwrite, no vmcnt drain
        cur ^= 1;
    }

    // ---- epilogue: combine lsum halves, normalize, write f16 out
    lsum += __shfl_xor(lsum, 32, 64);
    const int b = bh >> 4;
    const int h = bh & (H_ - 1);
    const float inv = 1.f / lsum;
    f16* outp = AO + ((size_t)(b * N_ + q0 + lo)) * C_ + h * D_;
    #pragma unroll
    for (int dh = 0; dh < 2; ++dh) {
        #pragma unroll
        for (int j2 = 0; j2 < 4; ++j2) {
            const int d0 = dh * 32 + 8 * j2 + 4 * hi;
            f16x4 st;
            #pragma unroll
            for (int e = 0; e < 4; ++e) {
                const float v = (dh == 0 ? o0[4 * j2 + e] : o1[4 * j2 + e]) * inv;
                st[e] = (f16)v;
            }
            *(f16x4*)(outp + d0) = st;
        }
    }
#undef STAGE_K
#undef P_TO_FRAGS
}

extern "C" void kernel_launch(void* const* d_in, const int* in_sizes, int n_in,
                              void* d_out, int out_size, void* d_ws, size_t ws_size,
                              hipStream_t stream) {
    const float* x         = (const float*)d_in[0];
    const float* qkv_w     = (const float*)d_in[1];
    const float* qkv_b     = (const float*)d_in[2];
    const float* bias_mask = (const float*)d_in[3];
    const float* proj_w    = (const float*)d_in[4];
    const float* proj_b    = (const float*)d_in[5];
    float* out = (float*)d_out;

    const size_t NE = (size_t)B_ * H_ * N_ * D_;   // 8388608
    f16* Xh  = (f16*)d_ws;          // NE
    f16* Wh  = Xh + NE;             // NW1_
    f16* Ph  = Wh + NW1_;           // NW2_
    f16* Qh  = Ph + NW2_;           // NE
    f16* Kh  = Qh + NE;             // NE
    f16* Vt  = Kh + NE;             // NE
    f16* AOh = Vt + NE;             // NE

    dim3 blk(256);
    convert_kernel<<<12288, blk, 0, stream>>>(x, qkv_w, proj_w, Xh, Wh, Ph);
    qkv_gemm_f16<<<dim3(64, 24), blk, 0, stream>>>(Xh, Wh, qkv_b, bias_mask, Qh, Kh, Vt);
    attn_fa17_kernel<<<dim3(512), dim3(512), 0, stream>>>(Qh, Kh, Vt, AOh);
    proj_gemm_f16<<<dim3(64, 8), blk, 0, stream>>>(AOh, Ph, proj_b, out);
}

// Round 27
// 217.541 us; speedup vs baseline: 1.2363x; 1.2363x over previous
//
#include <hip/hip_runtime.h>
#include <hip/hip_bf16.h>

#define B_ 4
#define N_ 2048
#define C_ 1024
#define H_ 16
#define D_ 64
#define QSCALE_ 0.1803368801f   /* 0.125 * log2(e): softmax uses exp2 */

typedef _Float16 f16;
typedef __attribute__((ext_vector_type(8))) _Float16 f16x8;
typedef __attribute__((ext_vector_type(4))) _Float16 f16x4;
typedef __attribute__((ext_vector_type(4))) float f32x4;
typedef __attribute__((ext_vector_type(16))) float f32x16;
typedef __attribute__((ext_vector_type(4))) int i32x4;
#define MFMA16(a, b, c) __builtin_amdgcn_mfma_f32_16x16x32_f16(a, b, c, 0, 0, 0)
#define MFMA32(a, b, c) __builtin_amdgcn_mfma_f32_32x32x16_f16(a, b, c, 0, 0, 0)

__device__ inline void gload_lds16(const f16* g, f16* l) {
    __builtin_amdgcn_global_load_lds(
        (const __attribute__((address_space(1))) void*)g,
        (__attribute__((address_space(3))) void*)l, 16, 0, 0);
}

__device__ inline int pkrtz(float a, float b) {
    return __builtin_bit_cast(int, __builtin_amdgcn_cvt_pkrtz(a, b));
}

// ---------------- f32 -> f16 convert (x, qkv_w, proj_w) ----------------
#define NX_ 8388608u
#define NW1_ 3145728u
#define NW2_ 1048576u

__global__ __launch_bounds__(256) void convert_kernel(
    const float* __restrict__ x, const float* __restrict__ w1, const float* __restrict__ w2,
    f16* __restrict__ xo, f16* __restrict__ w1o, f16* __restrict__ w2o)
{
    const unsigned q = blockIdx.x * 256 + threadIdx.x;
    const unsigned i = q << 2;
    const float* src;
    f16* dst;
    if (i < NX_)              { src = x  + i;               dst = xo  + i; }
    else if (i < NX_ + NW1_)  { src = w1 + (i - NX_);       dst = w1o + (i - NX_); }
    else                      { src = w2 + (i - NX_ - NW1_); dst = w2o + (i - NX_ - NW1_); }
    const float4 v = *(const float4*)src;
    f16x4 h;
    h[0] = (f16)v.x; h[1] = (f16)v.y; h[2] = (f16)v.z; h[3] = (f16)v.w;
    *(f16x4*)dst = h;
}

// ---------------- f16 MFMA GEMM: C[m][o] = sum_k A[m][k] * W[o][k] ----------------
__global__ __launch_bounds__(256) void qkv_gemm_f16(
    const f16* __restrict__ Xh,        // [8192][1024]
    const f16* __restrict__ Wh,        // [3072][1024]
    const float* __restrict__ qkv_b,
    const float* __restrict__ bias_mask,
    f16* __restrict__ Qh,              // [BH][N][D] (pre-scaled by QSCALE_)
    f16* __restrict__ Kh,              // [BH][N][D]
    f16* __restrict__ Vt)              // [BH][D][N]
{
    __shared__ f16 As[128 * 64];
    __shared__ f16 Bs[128 * 64];
    const int tid  = threadIdx.x;
    const int bm   = blockIdx.x * 128;
    const int bo   = blockIdx.y * 128;
    const int lane = tid & 63, lo = lane & 15, grp = lane >> 4;
    const int wave = tid >> 6, wr = wave >> 1, wc = wave & 1;
    const int sr = tid >> 3, cg = tid & 7;
    const int scol = (cg ^ (sr & 7)) << 3;

    f32x4 acc[4][4];
    #pragma unroll
    for (int m = 0; m < 4; ++m)
        #pragma unroll
        for (int n = 0; n < 4; ++n) acc[m][n] = f32x4{0.f, 0.f, 0.f, 0.f};

    for (int k0 = 0; k0 < 1024; k0 += 64) {
        #pragma unroll
        for (int i = 0; i < 4; ++i) {
            const int tr = i * 32 + sr;
            gload_lds16(Xh + (size_t)(bm + tr) * 1024 + k0 + scol, As + (i * 2048 + tid * 8));
            gload_lds16(Wh + (size_t)(bo + tr) * 1024 + k0 + scol, Bs + (i * 2048 + tid * 8));
        }
        __syncthreads();
        #pragma unroll
        for (int kh = 0; kh < 2; ++kh) {
            f16x8 af[4], bfr[4];
            #pragma unroll
            for (int m = 0; m < 4; ++m) {
                const int row = wr * 64 + m * 16 + lo;
                af[m] = *(const f16x8*)(As + row * 64 + ((((kh << 2) + grp) << 3) ^ ((row & 7) << 3)));
            }
            #pragma unroll
            for (int n = 0; n < 4; ++n) {
                const int row = wc * 64 + n * 16 + lo;
                bfr[n] = *(const f16x8*)(Bs + row * 64 + ((((kh << 2) + grp) << 3) ^ ((row & 7) << 3)));
            }
            #pragma unroll
            for (int m = 0; m < 4; ++m)
                #pragma unroll
                for (int n = 0; n < 4; ++n)
                    acc[m][n] = MFMA16(af[m], bfr[n], acc[m][n]);
        }
        __syncthreads();
    }
    #pragma unroll
    for (int ni = 0; ni < 4; ++ni) {
        const int o = bo + wc * 64 + ni * 16 + lo;
        const float bias = qkv_b[o] * bias_mask[o];
        const int s = o >> 10, h = (o >> 6) & 15, d = o & 63;
        #pragma unroll
        for (int mi = 0; mi < 4; ++mi) {
            #pragma unroll
            for (int r = 0; r < 4; ++r) {
                const int m = bm + wr * 64 + mi * 16 + grp * 4 + r;
                const int b = m >> 11, n = m & (N_ - 1);
                const int bh = b * H_ + h;
                const float val = acc[mi][ni][r] + bias;
                if (s == 0)      Qh[((size_t)bh * N_ + n) * D_ + d] = (f16)(val * QSCALE_);
                else if (s == 1) Kh[((size_t)bh * N_ + n) * D_ + d] = (f16)val;
                else             Vt[((size_t)bh * D_ + d) * N_ + n] = (f16)val;
            }
        }
    }
}

__global__ __launch_bounds__(256) void proj_gemm_f16(
    const f16* __restrict__ Ah,        // [8192][1024] attn out
    const f16* __restrict__ Wh,        // [1024][1024]
    const float* __restrict__ proj_b,
    float* __restrict__ Out)           // [8192][1024] f32
{
    __shared__ f16 As[128 * 64];
    __shared__ f16 Bs[128 * 64];
    const int tid  = threadIdx.x;
    const int bm   = blockIdx.x * 128;
    const int bo   = blockIdx.y * 128;
    const int lane = tid & 63, lo = lane & 15, grp = lane >> 4;
    const int wave = tid >> 6, wr = wave >> 1, wc = wave & 1;
    const int sr = tid >> 3, cg = tid & 7;
    const int scol = (cg ^ (sr & 7)) << 3;

    f32x4 acc[4][4];
    #pragma unroll
    for (int m = 0; m < 4; ++m)
        #pragma unroll
        for (int n = 0; n < 4; ++n) acc[m][n] = f32x4{0.f, 0.f, 0.f, 0.f};

    for (int k0 = 0; k0 < 1024; k0 += 64) {
        #pragma unroll
        for (int i = 0; i < 4; ++i) {
            const int tr = i * 32 + sr;
            gload_lds16(Ah + (size_t)(bm + tr) * 1024 + k0 + scol, As + (i * 2048 + tid * 8));
            gload_lds16(Wh + (size_t)(bo + tr) * 1024 + k0 + scol, Bs + (i * 2048 + tid * 8));
        }
        __syncthreads();
        #pragma unroll
        for (int kh = 0; kh < 2; ++kh) {
            f16x8 af[4], bfr[4];
            #pragma unroll
            for (int m = 0; m < 4; ++m) {
                const int row = wr * 64 + m * 16 + lo;
                af[m] = *(const f16x8*)(As + row * 64 + ((((kh << 2) + grp) << 3) ^ ((row & 7) << 3)));
            }
            #pragma unroll
            for (int n = 0; n < 4; ++n) {
                const int row = wc * 64 + n * 16 + lo;
                bfr[n] = *(const f16x8*)(Bs + row * 64 + ((((kh << 2) + grp) << 3) ^ ((row & 7) << 3)));
            }
            #pragma unroll
            for (int m = 0; m < 4; ++m)
                #pragma unroll
                for (int n = 0; n < 4; ++n)
                    acc[m][n] = MFMA16(af[m], bfr[n], acc[m][n]);
        }
        __syncthreads();
    }
    #pragma unroll
    for (int ni = 0; ni < 4; ++ni) {
        const int o = bo + wc * 64 + ni * 16 + lo;
        const float pb = proj_b[o];
        #pragma unroll
        for (int mi = 0; mi < 4; ++mi) {
            #pragma unroll
            for (int r = 0; r < 4; ++r) {
                const int m = bm + wr * 64 + mi * 16 + grp * 4 + r;
                Out[(size_t)m * C_ + o] = acc[mi][ni][r] + pb;
            }
        }
    }
}

// ---------------- 8-wave KVBLK=128 register-P flash attention (attn_fa16, session best) ----------------
__global__ __launch_bounds__(512) void attn_fa16_kernel(
    const f16* __restrict__ Qb,  // [BH][N][D] (scaled by QSCALE_)
    const f16* __restrict__ Kb,  // [BH][N][D]
    const f16* __restrict__ Vt,  // [BH][D][N]
    f16* __restrict__ AO)        // [B][N][C] f16
{
    __shared__ f16 Kt[2][128 * 64];
    __shared__ f16 Vb2[2][64 * 128];
    const int tid  = threadIdx.x;
    const int lane = tid & 63;
    const int lo   = lane & 31;
    const int hi   = lane >> 5;
    const int wave = tid >> 6;               // 0..7

    const int id   = blockIdx.x;             // 0..511
    const int xcd  = id & 7;
    const int j    = id >> 3;                // 0..63
    const int bh   = (xcd << 3) | (j >> 3);  // 8 heads per XCD (L2-resident K/V)
    const int q0   = (j & 7) * 256 + wave * 32;
    const size_t base = (size_t)bh * (N_ * D_);

    const f16* Kp = Kb + base;
    const f16* Vp = Vt + base;

    f16x8 qf[4];
    #pragma unroll
    for (int dc = 0; dc < 4; ++dc)
        qf[dc] = *(const f16x8*)(Qb + base + (size_t)(q0 + lo) * D_ + dc * 16 + hi * 8);

    // stage a 128-kv tile pair: K 1024 slots (2/thread), V 1024 slots (2/thread).
#define STAGE_KV(BK, BV, KV0)                                                      \
    { _Pragma("unroll") for (int i_ = 0; i_ < 2; ++i_) {                           \
        const int si_ = i_ * 512 + tid;                                            \
        const int krow_ = si_ >> 3, kgrp_ = si_ & 7;                               \
        gload_lds16(Kp + (size_t)((KV0) + krow_) * D_ + ((kgrp_ ^ (krow_ & 7)) << 3), \
                    (BK) + si_ * 8);                                               \
        const int vrow_ = si_ >> 4, vslt_ = si_ & 15;                              \
        gload_lds16(Vp + (size_t)vrow_ * N_ + (KV0) + ((vslt_ ^ (vrow_ & 15)) << 3), \
                    (BV) + si_ * 8);                                               \
      } }

// in-register P redistribution (validated in fa14/fa15/fa16)
#define P_TO_FRAGS(P, PB1, PB2)                                                    \
    { int d0_ = pkrtz(P[0],  P[1]),  d1_ = pkrtz(P[2],  P[3]);                     \
      int d2_ = pkrtz(P[4],  P[5]),  d3_ = pkrtz(P[6],  P[7]);                     \
      int d4_ = pkrtz(P[8],  P[9]),  d5_ = pkrtz(P[10], P[11]);                    \
      int d6_ = pkrtz(P[12], P[13]), d7_ = pkrtz(P[14], P[15]);                    \
      const int x0_ = __shfl_xor(d0_, 32, 64), x1_ = __shfl_xor(d1_, 32, 64);      \
      const int x2_ = __shfl_xor(d2_, 32, 64), x3_ = __shfl_xor(d3_, 32, 64);      \
      const int x4_ = __shfl_xor(d4_, 32, 64), x5_ = __shfl_xor(d5_, 32, 64);      \
      const int x6_ = __shfl_xor(d6_, 32, 64), x7_ = __shfl_xor(d7_, 32, 64);      \
      i32x4 w1_, w2_;                                                              \
      w1_[0] = hi ? x2_ : d0_;  w1_[1] = hi ? x3_ : d1_;                           \
      w1_[2] = hi ? d2_ : x0_;  w1_[3] = hi ? d3_ : x1_;                           \
      w2_[0] = hi ? x6_ : d4_;  w2_[1] = hi ? x7_ : d5_;                           \
      w2_[2] = hi ? d6_ : x4_;  w2_[3] = hi ? d7_ : x5_;                           \
      PB1 = __builtin_bit_cast(f16x8, w1_);                                        \
      PB2 = __builtin_bit_cast(f16x8, w2_); }

    const f32x16 zero16 = {};
    f32x16 o0 = zero16, o1 = zero16;   // O^T: reg r = O[d=(dh*32)+(r&3)+8(r>>2)+4hi][q=lo]
    float lsum = 0.f;                  // own-half partial; combined in epilogue
    const int kx = (lo & 7) << 3;      // K swizzle key
    const int vx = lo & 15;            // V swizzle key (4-bit)

    STAGE_KV(Kt[0], Vb2[0], 0);
    int cur = 0;

    for (int t = 0; t < 16; ++t) {
        const int nxt = (t < 15) ? (t + 1) * 128 : 0;
        STAGE_KV(Kt[cur ^ 1], Vb2[cur ^ 1], nxt);
        asm volatile("s_waitcnt vmcnt(4)" ::: "memory");   // tile t landed; next 4 in flight
        __builtin_amdgcn_s_barrier();
        __builtin_amdgcn_sched_barrier(0);

        const f16* kb = Kt[cur];
        const f16* vb = Vb2[cur];

        #pragma unroll
        for (int c = 0; c < 4; ++c) {
            f16x8 kf[4];
            #pragma unroll
            for (int dc = 0; dc < 4; ++dc)
                kf[dc] = *(const f16x8*)(kb + (c * 32 + lo) * 64 + ((((dc * 2 + hi) << 3)) ^ kx));
            __builtin_amdgcn_s_setprio(1);
            f32x16 s = MFMA32(kf[0], qf[0], zero16);
            s = MFMA32(kf[1], qf[1], s);
            s = MFMA32(kf[2], qf[2], s);
            s = MFMA32(kf[3], qf[3], s);
            __builtin_amdgcn_s_setprio(0);

            const f16x8 vf00 = *(const f16x8*)(vb + lo * 128 + (((c * 4 + hi) ^ vx) << 3));
            const f16x8 vf01 = *(const f16x8*)(vb + lo * 128 + (((c * 4 + 2 + hi) ^ vx) << 3));
            const f16x8 vf10 = *(const f16x8*)(vb + (32 + lo) * 128 + (((c * 4 + hi) ^ vx) << 3));
            const f16x8 vf11 = *(const f16x8*)(vb + (32 + lo) * 128 + (((c * 4 + 2 + hi) ^ vx) << 3));

            float p[16];
            #pragma unroll
            for (int r = 0; r < 16; ++r) p[r] = __builtin_amdgcn_exp2f(s[r]);
            lsum += (((p[0]+p[1])+(p[2]+p[3])) + ((p[4]+p[5])+(p[6]+p[7])))
                  + (((p[8]+p[9])+(p[10]+p[11])) + ((p[12]+p[13])+(p[14]+p[15])));
            f16x8 pb1, pb2;
            P_TO_FRAGS(p, pb1, pb2);

            __builtin_amdgcn_s_setprio(1);
            o0 = MFMA32(vf00, pb1, o0);
            o0 = MFMA32(vf01, pb2, o0);
            o1 = MFMA32(vf10, pb1, o1);
            o1 = MFMA32(vf11, pb2, o1);
            __builtin_amdgcn_s_setprio(0);
        }

        __builtin_amdgcn_sched_barrier(0);
        __builtin_amdgcn_s_barrier();      // raw: protect buffer overwrite, no vmcnt drain
        cur ^= 1;
    }

    // ---- epilogue: combine lsum halves, normalize, write f16 out
    lsum += __shfl_xor(lsum, 32, 64);
    const int b = bh >> 4;
    const int h = bh & (H_ - 1);
    const float inv = 1.f / lsum;
    f16* outp = AO + ((size_t)(b * N_ + q0 + lo)) * C_ + h * D_;
    #pragma unroll
    for (int dh = 0; dh < 2; ++dh) {
        #pragma unroll
        for (int j2 = 0; j2 < 4; ++j2) {
            const int d0 = dh * 32 + 8 * j2 + 4 * hi;
            f16x4 st;
            #pragma unroll
            for (int e = 0; e < 4; ++e) {
                const float v = (dh == 0 ? o0[4 * j2 + e] : o1[4 * j2 + e]) * inv;
                st[e] = (f16)v;
            }
            *(f16x4*)(outp + d0) = st;
        }
    }
#undef STAGE_KV
#undef P_TO_FRAGS
}

extern "C" void kernel_launch(void* const* d_in, const int* in_sizes, int n_in,
                              void* d_out, int out_size, void* d_ws, size_t ws_size,
                              hipStream_t stream) {
    const float* x         = (const float*)d_in[0];
    const float* qkv_w     = (const float*)d_in[1];
    const float* qkv_b     = (const float*)d_in[2];
    const float* bias_mask = (const float*)d_in[3];
    const float* proj_w    = (const float*)d_in[4];
    const float* proj_b    = (const float*)d_in[5];
    float* out = (float*)d_out;

    const size_t NE = (size_t)B_ * H_ * N_ * D_;   // 8388608
    f16* Xh  = (f16*)d_ws;          // NE
    f16* Wh  = Xh + NE;             // NW1_
    f16* Ph  = Wh + NW1_;           // NW2_
    f16* Qh  = Ph + NW2_;           // NE
    f16* Kh  = Qh + NE;             // NE
    f16* Vt  = Kh + NE;             // NE
    f16* AOh = Vt + NE;             // NE

    dim3 blk(256);
    convert_kernel<<<12288, blk, 0, stream>>>(x, qkv_w, proj_w, Xh, Wh, Ph);
    qkv_gemm_f16<<<dim3(64, 24), blk, 0, stream>>>(Xh, Wh, qkv_b, bias_mask, Qh, Kh, Vt);
    attn_fa16_kernel<<<dim3(512), dim3(512), 0, stream>>>(Qh, Kh, Vt, AOh);
    proj_gemm_f16<<<dim3(64, 8), blk, 0, stream>>>(AOh, Ph, proj_b, out);
}